// Round 4
// baseline (307.427 us; speedup 1.0000x reference)
//
#include <hip/hip_runtime.h>
#include <stdint.h>

#define F 128
#define KNB 16
#define TWO_F 256
#define ROWS 64          // rows per block
#define THREADS 256
#define XSTRIDE 264      // bf16 elems per x row (256 + 8 pad)
#define HSTR 133         // f32 stride of LN scratch rows
#define LN_EPS 1e-5f
#define NEG_SLOPE 0.2f

typedef unsigned short u16;
typedef __bf16 bf16x8 __attribute__((ext_vector_type(8)));
typedef float f32x4 __attribute__((ext_vector_type(4)));

union BF8 { bf16x8 v; u16 us[8]; uint4 u4; };

__device__ __forceinline__ float b2f(u16 u) {
    union { float f; uint32_t i; } v; v.i = ((uint32_t)u) << 16; return v.f;
}
__device__ __forceinline__ u16 f2b(float f) {
    union { float f; uint32_t i; } v; v.f = f;
    uint32_t r = (v.i + 0x7FFFu + ((v.i >> 16) & 1u)) >> 16;
    return (u16)r;
}

// one kernel casts both W (first wn8 chunks) and feat (next fn8 chunks), 8 f32 -> 8 bf16 per thread
extern "C" __global__ void cast_all(const float* __restrict__ W, const float* __restrict__ feat,
                                    u16* __restrict__ wsW, u16* __restrict__ wsF,
                                    int wn8, int fn8) {
    const int i = blockIdx.x * blockDim.x + threadIdx.x;
    const float4* s;
    uint4* d;
    if (i < wn8) {
        s = (const float4*)W + (size_t)i * 2;
        d = (uint4*)wsW + i;
    } else if (i - wn8 < fn8) {
        const int j = i - wn8;
        s = (const float4*)feat + (size_t)j * 2;
        d = (uint4*)wsF + j;
    } else return;
    const float4 a = s[0], b = s[1];
    BF8 o;
    o.us[0] = f2b(a.x); o.us[1] = f2b(a.y); o.us[2] = f2b(a.z); o.us[3] = f2b(a.w);
    o.us[4] = f2b(b.x); o.us[5] = f2b(b.y); o.us[6] = f2b(b.z); o.us[7] = f2b(b.w);
    *d = o.u4;
}

// MODE 0: all fp32 from global (no ws).  MODE 1: W from bf16 ws.  MODE 2: W + feat from bf16 ws.
template <int MODE>
__global__ __launch_bounds__(THREADS, 4)
void gnn_fused(const float* __restrict__ feat_f32, const u16* __restrict__ feat_bf,
               const int* __restrict__ adj,
               const float* __restrict__ W_f32, const u16* __restrict__ W_bf,
               const float* __restrict__ bias, const float* __restrict__ gamma,
               const float* __restrict__ beta,
               float* __restrict__ out, int N)
{
    __shared__ __align__(16) char smem[ROWS * XSTRIDE * 2 + ROWS * KNB * 4]; // 37888 B
    u16* xs   = (u16*)smem;                              // [64][264] bf16 x-tile
    int* adjs = (int*)(smem + ROWS * XSTRIDE * 2);       // [64][16]
    float* hb = (float*)smem;                            // epilogue overlay [64][HSTR] f32 (34048 B)

    const int tid = threadIdx.x;
    const long block0 = (long)blockIdx.x * ROWS;

    // ---- stage adjacency tile (1024 ints, 4 per thread) ----
    {
        const int flat = tid * 4;
        const long base = block0 * KNB + flat;
        const long total = (long)N * KNB;
        if (base + 3 < total) {
            *(int4*)(adjs + flat) = *(const int4*)(adj + base);
        } else {
            for (int j = 0; j < 4; ++j)
                adjs[flat + j] = (base + j < total) ? adj[base + j] : -1;
        }
    }
    __syncthreads();

    // ---- prologue: x = [own_feats | masked neighbor mean] as bf16 in LDS ----
    {
        const int r  = tid >> 2;          // row in tile 0..63
        const int q4 = tid & 3;           // 32-feature slice
        const long rg = block0 + r;
        const int fbase = q4 * 32;
        u16* xrow = xs + r * XSTRIDE;

        if (rg < N) {
            // own features
            if (MODE == 2) {
                const uint4* src = (const uint4*)(feat_bf + rg * F + fbase);
                uint4* dst = (uint4*)(xrow + fbase);
                #pragma unroll
                for (int j = 0; j < 4; ++j) dst[j] = src[j];
            } else {
                const float4* s = (const float4*)(feat_f32 + rg * F + fbase);
                uint4* dst = (uint4*)(xrow + fbase);
                #pragma unroll
                for (int j = 0; j < 4; ++j) {
                    const float4 a = s[j * 2], b = s[j * 2 + 1];
                    BF8 o;
                    o.us[0] = f2b(a.x); o.us[1] = f2b(a.y); o.us[2] = f2b(a.z); o.us[3] = f2b(a.w);
                    o.us[4] = f2b(b.x); o.us[5] = f2b(b.y); o.us[6] = f2b(b.z); o.us[7] = f2b(b.w);
                    dst[j] = o.u4;
                }
            }

            // neighbor gather-mean (BRANCHLESS: clamped index + 0/1 mask weight)
            float acc[32];
            #pragma unroll
            for (int t = 0; t < 32; ++t) acc[t] = 0.f;
            float fcnt = 0.f;

            #pragma unroll
            for (int k = 0; k < KNB; ++k) {
                const int idx = adjs[r * KNB + k];
                const float w = (idx >= 0) ? 1.f : 0.f;
                int ic = (idx >= 0) ? idx : 0;
                ic = (ic < N) ? ic : (N - 1);
                fcnt += w;
                if (MODE == 2) {
                    const uint4* ns = (const uint4*)(feat_bf + (size_t)ic * F + fbase);
                    #pragma unroll
                    for (int j = 0; j < 4; ++j) {
                        BF8 u; u.u4 = ns[j];
                        #pragma unroll
                        for (int t = 0; t < 8; ++t) acc[j * 8 + t] += w * b2f(u.us[t]);
                    }
                } else {
                    const float4* ns = (const float4*)(feat_f32 + (size_t)ic * F + fbase);
                    #pragma unroll
                    for (int j = 0; j < 8; ++j) {
                        const float4 a = ns[j];
                        acc[j * 4 + 0] += w * a.x; acc[j * 4 + 1] += w * a.y;
                        acc[j * 4 + 2] += w * a.z; acc[j * 4 + 3] += w * a.w;
                    }
                }
            }
            const float scale = 1.f / fmaxf(fcnt, 1.f);
            uint4* mdst = (uint4*)(xrow + F + fbase);
            #pragma unroll
            for (int j = 0; j < 4; ++j) {
                BF8 o;
                #pragma unroll
                for (int t = 0; t < 8; ++t) o.us[t] = f2b(acc[j * 8 + t] * scale);
                mdst[j] = o.u4;
            }
        } else {
            const uint4 z = make_uint4(0, 0, 0, 0);
            uint4* d0 = (uint4*)(xrow + fbase);
            uint4* d1 = (uint4*)(xrow + F + fbase);
            #pragma unroll
            for (int j = 0; j < 4; ++j) { d0[j] = z; d1[j] = z; }
        }
    }
    __syncthreads();

    // ---- GEMM: each wave computes h[16 rows x 128 cols] via mfma 16x16x32 bf16 ----
    const int wave = tid >> 6;
    const int lane = tid & 63;
    const int ln15 = lane & 15;
    const int quad = lane >> 4;
    const int rb   = wave * 16;

    f32x4 accf[8];
    #pragma unroll
    for (int c = 0; c < 8; ++c) accf[c] = (f32x4){0.f, 0.f, 0.f, 0.f};

    const u16* arow = xs + (rb + ln15) * XSTRIDE + quad * 8;

    #pragma unroll
    for (int ks = 0; ks < 8; ++ks) {
        const bf16x8 afrag = *(const bf16x8*)(arow + ks * 32);
        #pragma unroll
        for (int c = 0; c < 8; ++c) {
            bf16x8 bfrag;
            if (MODE >= 1) {
                bfrag = *(const bf16x8*)(W_bf + (size_t)(c * 16 + ln15) * TWO_F + quad * 8 + ks * 32);
            } else {
                const float* wr = W_f32 + (size_t)(c * 16 + ln15) * TWO_F + quad * 8 + ks * 32;
                const float4 a = *(const float4*)wr, b = *(const float4*)(wr + 4);
                BF8 o;
                o.us[0] = f2b(a.x); o.us[1] = f2b(a.y); o.us[2] = f2b(a.z); o.us[3] = f2b(a.w);
                o.us[4] = f2b(b.x); o.us[5] = f2b(b.y); o.us[6] = f2b(b.z); o.us[7] = f2b(b.w);
                bfrag = o.v;
            }
            accf[c] = __builtin_amdgcn_mfma_f32_16x16x32_bf16(afrag, bfrag, accf[c], 0, 0, 0);
        }
    }

    // bias per (col-tile, lane-col)
    float bval[8];
    #pragma unroll
    for (int c = 0; c < 8; ++c) bval[c] = bias[c * 16 + ln15];

    // xs no longer needed; overlay hb (crosses wave regions -> barrier first)
    __syncthreads();

    // ---- write h to LDS scratch (C/D layout: col = lane&15, row = quad*4 + reg) ----
    #pragma unroll
    for (int c = 0; c < 8; ++c) {
        #pragma unroll
        for (int t = 0; t < 4; ++t) {
            const int rr = quad * 4 + t;
            hb[(rb + rr) * HSTR + c * 16 + ln15] = accf[c][t] + bval[c];
        }
    }
    __syncthreads();

    // ---- LayerNorm + LeakyReLU: 4 lanes per row ----
    const int er = lane >> 2;                  // row 0..15 (within wave slice)
    const int eq = lane & 3;                   // 32-col slice
    const float* hr = hb + (rb + er) * HSTR + eq * 32;
    float sum = 0.f, sq = 0.f;
    #pragma unroll
    for (int t = 0; t < 32; ++t) { const float v = hr[t]; sum += v; sq += v * v; }
    sum += __shfl_xor(sum, 1); sq += __shfl_xor(sq, 1);
    sum += __shfl_xor(sum, 2); sq += __shfl_xor(sq, 2);

    const float mu   = sum * (1.f / 128.f);
    const float var  = sq * (1.f / 128.f) - mu * mu;
    const float rsig = rsqrtf(fmaxf(var, 0.f) + LN_EPS);

    const long org = block0 + rb + er;
    if (org < N) {
        const int cb = eq * 32;
        float* orow = out + org * F + cb;
        #pragma unroll
        for (int j = 0; j < 8; ++j) {
            const float4 g  = *(const float4*)(gamma + cb + j * 4);
            const float4 bt = *(const float4*)(beta  + cb + j * 4);
            float4 o;
            o.x = (hr[j * 4 + 0] - mu) * rsig * g.x + bt.x;
            o.y = (hr[j * 4 + 1] - mu) * rsig * g.y + bt.y;
            o.z = (hr[j * 4 + 2] - mu) * rsig * g.z + bt.z;
            o.w = (hr[j * 4 + 3] - mu) * rsig * g.w + bt.w;
            o.x = (o.x >= 0.f) ? o.x : NEG_SLOPE * o.x;
            o.y = (o.y >= 0.f) ? o.y : NEG_SLOPE * o.y;
            o.z = (o.z >= 0.f) ? o.z : NEG_SLOPE * o.z;
            o.w = (o.w >= 0.f) ? o.w : NEG_SLOPE * o.w;
            *(float4*)(orow + j * 4) = o;
        }
    }
}

extern "C" void kernel_launch(void* const* d_in, const int* in_sizes, int n_in,
                              void* d_out, int out_size, void* d_ws, size_t ws_size,
                              hipStream_t stream) {
    const float* feat  = (const float*)d_in[0];
    const int*   adj   = (const int*)d_in[1];
    const float* W     = (const float*)d_in[2];
    const float* bias  = (const float*)d_in[3];
    const float* gamma = (const float*)d_in[4];
    const float* beta  = (const float*)d_in[5];
    float* out = (float*)d_out;

    const int N = in_sizes[0] / F;
    const size_t needW = (size_t)TWO_F * F * sizeof(u16);        // 64 KiB
    const size_t needF = (size_t)N * F * sizeof(u16);            // ~25.6 MB
    u16* wsW = (u16*)d_ws;
    u16* wsF = (u16*)((char*)d_ws + needW);

    const int mode = (ws_size >= needW + needF) ? 2 : (ws_size >= needW ? 1 : 0);

    if (mode >= 1) {
        const int wn8 = TWO_F * F / 8;
        const int fn8 = (mode == 2) ? (N * F / 8) : 0;
        const int tot = wn8 + fn8;
        cast_all<<<dim3((tot + 255) / 256), dim3(256), 0, stream>>>(W, feat, wsW, wsF, wn8, fn8);
    }

    const int blocks = (N + ROWS - 1) / ROWS;
    if (mode == 2) {
        gnn_fused<2><<<dim3(blocks), dim3(THREADS), 0, stream>>>(feat, wsF, adj, W, wsW, bias, gamma, beta, out, N);
    } else if (mode == 1) {
        gnn_fused<1><<<dim3(blocks), dim3(THREADS), 0, stream>>>(feat, wsF, adj, W, wsW, bias, gamma, beta, out, N);
    } else {
        gnn_fused<0><<<dim3(blocks), dim3(THREADS), 0, stream>>>(feat, wsF, adj, W, wsW, bias, gamma, beta, out, N);
    }
}

// Round 5
// 246.812 us; speedup vs baseline: 1.2456x; 1.2456x over previous
//
#include <hip/hip_runtime.h>
#include <stdint.h>

#define F 128
#define KNB 16
#define TWO_F 256
#define ROWS 64          // rows per block (fused + gemm_ln)
#define THREADS 256
#define XSTRIDE 264      // bf16 elems per x row (256 + 8 pad) in fused fallback
#define HSTR 133         // f32 stride of LN scratch rows
#define LN_EPS 1e-5f
#define NEG_SLOPE 0.2f

typedef unsigned short u16;
typedef __bf16 bf16x8 __attribute__((ext_vector_type(8)));
typedef float f32x4 __attribute__((ext_vector_type(4)));

union BF8 { bf16x8 v; u16 us[8]; uint4 u4; };

__device__ __forceinline__ float b2f(u16 u) {
    union { float f; uint32_t i; } v; v.i = ((uint32_t)u) << 16; return v.f;
}
__device__ __forceinline__ u16 f2b(float f) {
    union { float f; uint32_t i; } v; v.f = f;
    uint32_t r = (v.i + 0x7FFFu + ((v.i >> 16) & 1u)) >> 16;
    return (u16)r;
}

// casts W (first wn8 16B-chunks) and feat (next fn8 chunks) f32 -> bf16
extern "C" __global__ void cast_all(const float* __restrict__ W, const float* __restrict__ feat,
                                    u16* __restrict__ wsW, u16* __restrict__ wsF,
                                    int wn8, int fn8) {
    const int i = blockIdx.x * blockDim.x + threadIdx.x;
    const float4* s;
    uint4* d;
    if (i < wn8) {
        s = (const float4*)W + (size_t)i * 2;
        d = (uint4*)wsW + i;
    } else if (i - wn8 < fn8) {
        const int j = i - wn8;
        s = (const float4*)feat + (size_t)j * 2;
        d = (uint4*)wsF + j;
    } else return;
    const float4 a = s[0], b = s[1];
    BF8 o;
    o.us[0] = f2b(a.x); o.us[1] = f2b(a.y); o.us[2] = f2b(a.z); o.us[3] = f2b(a.w);
    o.us[4] = f2b(b.x); o.us[5] = f2b(b.y); o.us[6] = f2b(b.z); o.us[7] = f2b(b.w);
    *d = o.u4;
}

// ---- Kernel A: gather + masked mean -> x bf16 [padN][256] in ws ----
// 16 threads per row; thread handles an 8-feature slice. No LDS, small state.
extern "C" __global__ __launch_bounds__(256)
void gather_x(const u16* __restrict__ wsF, const int* __restrict__ adj,
              u16* __restrict__ wsX, int N)
{
    const int tid  = threadIdx.x;
    const int lane = tid & 63;
    const long row = (long)blockIdx.x * 16 + (tid >> 4);
    if (row >= N) return;                       // whole 16-lane group exits together
    const int s8    = (lane & 15) * 8;          // feature slice base
    const int gbase = lane & 48;                // 16-lane group base within wave

    // one coalesced adj read per thread; k-th neighbor obtained by shfl
    const int my = adj[row * KNB + (lane & 15)];

    // own features: bf16 passthrough
    *(uint4*)(wsX + row * TWO_F + s8) = *(const uint4*)(wsF + row * F + s8);

    float acc[8];
    #pragma unroll
    for (int t = 0; t < 8; ++t) acc[t] = 0.f;
    float fcnt = 0.f;

    #pragma unroll 4
    for (int k = 0; k < KNB; ++k) {
        const int nk = __shfl(my, gbase | k);
        const float w = (nk >= 0) ? 1.f : 0.f;
        int ic = (nk >= 0) ? nk : 0;
        ic = (ic < N) ? ic : (N - 1);
        fcnt += w;
        BF8 u; u.u4 = *(const uint4*)(wsF + (size_t)ic * F + s8);
        #pragma unroll
        for (int t = 0; t < 8; ++t) acc[t] += w * b2f(u.us[t]);
    }

    const float scale = 1.f / fmaxf(fcnt, 1.f);
    BF8 o;
    #pragma unroll
    for (int t = 0; t < 8; ++t) o.us[t] = f2b(acc[t] * scale);
    *(uint4*)(wsX + row * TWO_F + F + s8) = o.u4;
}

// ---- Kernel B: GEMM + bias + LayerNorm + LeakyReLU (R2-verified mappings) ----
extern "C" __global__ __launch_bounds__(THREADS, 4)
void gemm_ln(const u16* __restrict__ wsX, const u16* __restrict__ wsW,
             const float* __restrict__ bias, const float* __restrict__ gamma,
             const float* __restrict__ beta, float* __restrict__ out, int N)
{
    __shared__ float hb[ROWS * HSTR];           // 34048 B LN scratch

    const int tid  = threadIdx.x;
    const long block0 = (long)blockIdx.x * ROWS;
    const int wave = tid >> 6;
    const int lane = tid & 63;
    const int ln15 = lane & 15;
    const int quad = lane >> 4;
    const int rb   = wave * 16;

    f32x4 accf[8];
    #pragma unroll
    for (int c = 0; c < 8; ++c) accf[c] = (f32x4){0.f, 0.f, 0.f, 0.f};

    // A-frags direct from global x (wsX padded to grid*64 rows)
    const u16* arow = wsX + (block0 + rb + ln15) * TWO_F + quad * 8;

    #pragma unroll
    for (int ks = 0; ks < 8; ++ks) {
        const bf16x8 afrag = *(const bf16x8*)(arow + ks * 32);
        #pragma unroll
        for (int c = 0; c < 8; ++c) {
            const bf16x8 bfrag = *(const bf16x8*)(wsW + (size_t)(c * 16 + ln15) * TWO_F + quad * 8 + ks * 32);
            accf[c] = __builtin_amdgcn_mfma_f32_16x16x32_bf16(afrag, bfrag, accf[c], 0, 0, 0);
        }
    }

    float bval[8];
    #pragma unroll
    for (int c = 0; c < 8; ++c) bval[c] = bias[c * 16 + ln15];

    // C/D layout: col = lane&15, row = quad*4 + reg  (verified R2)
    #pragma unroll
    for (int c = 0; c < 8; ++c) {
        #pragma unroll
        for (int t = 0; t < 4; ++t) {
            const int rr = quad * 4 + t;
            hb[(rb + rr) * HSTR + c * 16 + ln15] = accf[c][t] + bval[c];
        }
    }
    __syncthreads();

    const int er = lane >> 2;                   // row 0..15 within wave slice
    const int eq = lane & 3;                    // 32-col slice
    const float* hr = hb + (rb + er) * HSTR + eq * 32;
    float sum = 0.f, sq = 0.f;
    #pragma unroll
    for (int t = 0; t < 32; ++t) { const float v = hr[t]; sum += v; sq += v * v; }
    sum += __shfl_xor(sum, 1); sq += __shfl_xor(sq, 1);
    sum += __shfl_xor(sum, 2); sq += __shfl_xor(sq, 2);

    const float mu   = sum * (1.f / 128.f);
    const float var  = sq * (1.f / 128.f) - mu * mu;
    const float rsig = rsqrtf(fmaxf(var, 0.f) + LN_EPS);

    const long org = block0 + rb + er;
    if (org < N) {
        const int cb = eq * 32;
        float* orow = out + org * F + cb;
        #pragma unroll
        for (int j = 0; j < 8; ++j) {
            const float4 g  = *(const float4*)(gamma + cb + j * 4);
            const float4 bt = *(const float4*)(beta  + cb + j * 4);
            float4 o;
            o.x = (hr[j * 4 + 0] - mu) * rsig * g.x + bt.x;
            o.y = (hr[j * 4 + 1] - mu) * rsig * g.y + bt.y;
            o.z = (hr[j * 4 + 2] - mu) * rsig * g.z + bt.z;
            o.w = (hr[j * 4 + 3] - mu) * rsig * g.w + bt.w;
            o.x = (o.x >= 0.f) ? o.x : NEG_SLOPE * o.x;
            o.y = (o.y >= 0.f) ? o.y : NEG_SLOPE * o.y;
            o.z = (o.z >= 0.f) ? o.z : NEG_SLOPE * o.z;
            o.w = (o.w >= 0.f) ? o.w : NEG_SLOPE * o.w;
            *(float4*)(orow + j * 4) = o;
        }
    }
}

// ---- Fallback: R2's verified fused kernel (branchy gather), modes 0/1/2 ----
template <int MODE>
__global__ __launch_bounds__(THREADS, 4)
void gnn_fused(const float* __restrict__ feat_f32, const u16* __restrict__ feat_bf,
               const int* __restrict__ adj,
               const float* __restrict__ W_f32, const u16* __restrict__ W_bf,
               const float* __restrict__ bias, const float* __restrict__ gamma,
               const float* __restrict__ beta,
               float* __restrict__ out, int N)
{
    __shared__ __align__(16) char smem[ROWS * XSTRIDE * 2 + ROWS * KNB * 4];
    u16* xs   = (u16*)smem;
    int* adjs = (int*)(smem + ROWS * XSTRIDE * 2);
    float* hb = (float*)smem;

    const int tid = threadIdx.x;
    const long block0 = (long)blockIdx.x * ROWS;

    {
        const int flat = tid * 4;
        const long base = block0 * KNB + flat;
        const long total = (long)N * KNB;
        if (base + 3 < total) {
            *(int4*)(adjs + flat) = *(const int4*)(adj + base);
        } else {
            for (int j = 0; j < 4; ++j)
                adjs[flat + j] = (base + j < total) ? adj[base + j] : -1;
        }
    }
    __syncthreads();

    {
        const int r  = tid >> 2;
        const int q4 = tid & 3;
        const long rg = block0 + r;
        const int fbase = q4 * 32;
        u16* xrow = xs + r * XSTRIDE;

        if (rg < N) {
            if (MODE == 2) {
                const uint4* src = (const uint4*)(feat_bf + rg * F + fbase);
                uint4* dst = (uint4*)(xrow + fbase);
                #pragma unroll
                for (int j = 0; j < 4; ++j) dst[j] = src[j];
            } else {
                const float4* s = (const float4*)(feat_f32 + rg * F + fbase);
                uint4* dst = (uint4*)(xrow + fbase);
                #pragma unroll
                for (int j = 0; j < 4; ++j) {
                    const float4 a = s[j * 2], b = s[j * 2 + 1];
                    BF8 o;
                    o.us[0] = f2b(a.x); o.us[1] = f2b(a.y); o.us[2] = f2b(a.z); o.us[3] = f2b(a.w);
                    o.us[4] = f2b(b.x); o.us[5] = f2b(b.y); o.us[6] = f2b(b.z); o.us[7] = f2b(b.w);
                    dst[j] = o.u4;
                }
            }

            float acc[32];
            #pragma unroll
            for (int t = 0; t < 32; ++t) acc[t] = 0.f;
            int cnt = 0;
            for (int k = 0; k < KNB; ++k) {
                const int idx = adjs[r * KNB + k];
                if (idx >= 0 && idx < N) {
                    ++cnt;
                    if (MODE == 2) {
                        const uint4* ns = (const uint4*)(feat_bf + (size_t)idx * F + fbase);
                        #pragma unroll
                        for (int j = 0; j < 4; ++j) {
                            BF8 u; u.u4 = ns[j];
                            #pragma unroll
                            for (int t = 0; t < 8; ++t) acc[j * 8 + t] += b2f(u.us[t]);
                        }
                    } else {
                        const float4* ns = (const float4*)(feat_f32 + (size_t)idx * F + fbase);
                        #pragma unroll
                        for (int j = 0; j < 8; ++j) {
                            const float4 a = ns[j];
                            acc[j * 4 + 0] += a.x; acc[j * 4 + 1] += a.y;
                            acc[j * 4 + 2] += a.z; acc[j * 4 + 3] += a.w;
                        }
                    }
                }
            }
            const float scale = 1.f / (float)(cnt > 0 ? cnt : 1);
            uint4* mdst = (uint4*)(xrow + F + fbase);
            #pragma unroll
            for (int j = 0; j < 4; ++j) {
                BF8 o;
                #pragma unroll
                for (int t = 0; t < 8; ++t) o.us[t] = f2b(acc[j * 8 + t] * scale);
                mdst[j] = o.u4;
            }
        } else {
            const uint4 z = make_uint4(0, 0, 0, 0);
            uint4* d0 = (uint4*)(xrow + fbase);
            uint4* d1 = (uint4*)(xrow + F + fbase);
            #pragma unroll
            for (int j = 0; j < 4; ++j) { d0[j] = z; d1[j] = z; }
        }
    }
    __syncthreads();

    const int wave = tid >> 6;
    const int lane = tid & 63;
    const int ln15 = lane & 15;
    const int quad = lane >> 4;
    const int rb   = wave * 16;

    f32x4 accf[8];
    #pragma unroll
    for (int c = 0; c < 8; ++c) accf[c] = (f32x4){0.f, 0.f, 0.f, 0.f};

    const u16* arow = xs + (rb + ln15) * XSTRIDE + quad * 8;

    #pragma unroll
    for (int ks = 0; ks < 8; ++ks) {
        const bf16x8 afrag = *(const bf16x8*)(arow + ks * 32);
        #pragma unroll
        for (int c = 0; c < 8; ++c) {
            bf16x8 bfrag;
            if (MODE >= 1) {
                bfrag = *(const bf16x8*)(W_bf + (size_t)(c * 16 + ln15) * TWO_F + quad * 8 + ks * 32);
            } else {
                const float* wr = W_f32 + (size_t)(c * 16 + ln15) * TWO_F + quad * 8 + ks * 32;
                const float4 a = *(const float4*)wr, b = *(const float4*)(wr + 4);
                BF8 o;
                o.us[0] = f2b(a.x); o.us[1] = f2b(a.y); o.us[2] = f2b(a.z); o.us[3] = f2b(a.w);
                o.us[4] = f2b(b.x); o.us[5] = f2b(b.y); o.us[6] = f2b(b.z); o.us[7] = f2b(b.w);
                bfrag = o.v;
            }
            accf[c] = __builtin_amdgcn_mfma_f32_16x16x32_bf16(afrag, bfrag, accf[c], 0, 0, 0);
        }
    }

    float bval[8];
    #pragma unroll
    for (int c = 0; c < 8; ++c) bval[c] = bias[c * 16 + ln15];

    __syncthreads();

    #pragma unroll
    for (int c = 0; c < 8; ++c) {
        #pragma unroll
        for (int t = 0; t < 4; ++t) {
            const int rr = quad * 4 + t;
            hb[(rb + rr) * HSTR + c * 16 + ln15] = accf[c][t] + bval[c];
        }
    }
    __syncthreads();

    const int er = lane >> 2;
    const int eq = lane & 3;
    const float* hr = hb + (rb + er) * HSTR + eq * 32;
    float sum = 0.f, sq = 0.f;
    #pragma unroll
    for (int t = 0; t < 32; ++t) { const float v = hr[t]; sum += v; sq += v * v; }
    sum += __shfl_xor(sum, 1); sq += __shfl_xor(sq, 1);
    sum += __shfl_xor(sum, 2); sq += __shfl_xor(sq, 2);

    const float mu   = sum * (1.f / 128.f);
    const float var  = sq * (1.f / 128.f) - mu * mu;
    const float rsig = rsqrtf(fmaxf(var, 0.f) + LN_EPS);

    const long org = block0 + rb + er;
    if (org < N) {
        const int cb = eq * 32;
        float* orow = out + org * F + cb;
        #pragma unroll
        for (int j = 0; j < 8; ++j) {
            const float4 g  = *(const float4*)(gamma + cb + j * 4);
            const float4 bt = *(const float4*)(beta  + cb + j * 4);
            float4 o;
            o.x = (hr[j * 4 + 0] - mu) * rsig * g.x + bt.x;
            o.y = (hr[j * 4 + 1] - mu) * rsig * g.y + bt.y;
            o.z = (hr[j * 4 + 2] - mu) * rsig * g.z + bt.z;
            o.w = (hr[j * 4 + 3] - mu) * rsig * g.w + bt.w;
            o.x = (o.x >= 0.f) ? o.x : NEG_SLOPE * o.x;
            o.y = (o.y >= 0.f) ? o.y : NEG_SLOPE * o.y;
            o.z = (o.z >= 0.f) ? o.z : NEG_SLOPE * o.z;
            o.w = (o.w >= 0.f) ? o.w : NEG_SLOPE * o.w;
            *(float4*)(orow + j * 4) = o;
        }
    }
}

extern "C" void kernel_launch(void* const* d_in, const int* in_sizes, int n_in,
                              void* d_out, int out_size, void* d_ws, size_t ws_size,
                              hipStream_t stream) {
    const float* feat  = (const float*)d_in[0];
    const int*   adj   = (const int*)d_in[1];
    const float* W     = (const float*)d_in[2];
    const float* bias  = (const float*)d_in[3];
    const float* gamma = (const float*)d_in[4];
    const float* beta  = (const float*)d_in[5];
    float* out = (float*)d_out;

    const int N = in_sizes[0] / F;
    const int gblocks = (N + ROWS - 1) / ROWS;           // gemm_ln grid
    const long padN = (long)gblocks * ROWS;              // x rows incl. pad

    const size_t needW = (size_t)TWO_F * F * sizeof(u16);        // 64 KiB
    const size_t needF = (size_t)N * F * sizeof(u16);            // ~25.6 MB
    const size_t needX = (size_t)padN * TWO_F * sizeof(u16);     // ~51.2 MB
    u16* wsW = (u16*)d_ws;
    u16* wsF = (u16*)((char*)d_ws + needW);
    u16* wsX = (u16*)((char*)d_ws + needW + needF);

    if (ws_size >= needW + needF + needX) {
        // split pipeline: cast -> gather -> gemm+ln
        const int wn8 = TWO_F * F / 8;
        const int fn8 = N * F / 8;
        const int tot = wn8 + fn8;
        cast_all<<<dim3((tot + 255) / 256), dim3(256), 0, stream>>>(W, feat, wsW, wsF, wn8, fn8);
        gather_x<<<dim3((N + 15) / 16), dim3(256), 0, stream>>>(wsF, adj, wsX, N);
        gemm_ln<<<dim3(gblocks), dim3(THREADS), 0, stream>>>(wsX, wsW, bias, gamma, beta, out, N);
        return;
    }

    const int mode = (ws_size >= needW + needF) ? 2 : (ws_size >= needW ? 1 : 0);
    if (mode >= 1) {
        const int wn8 = TWO_F * F / 8;
        const int fn8 = (mode == 2) ? (N * F / 8) : 0;
        const int tot = wn8 + fn8;
        cast_all<<<dim3((tot + 255) / 256), dim3(256), 0, stream>>>(W, feat, wsW, wsF, wn8, fn8);
    }
    if (mode == 2) {
        gnn_fused<2><<<dim3(gblocks), dim3(THREADS), 0, stream>>>(feat, wsF, adj, W, wsW, bias, gamma, beta, out, N);
    } else if (mode == 1) {
        gnn_fused<1><<<dim3(gblocks), dim3(THREADS), 0, stream>>>(feat, wsF, adj, W, wsW, bias, gamma, beta, out, N);
    } else {
        gnn_fused<0><<<dim3(gblocks), dim3(THREADS), 0, stream>>>(feat, wsF, adj, W, wsW, bias, gamma, beta, out, N);
    }
}